// Round 2
// baseline (648.556 us; speedup 1.0000x reference)
//
#include <hip/hip_runtime.h>
#include <hip/hip_cooperative_groups.h>

namespace cg = cooperative_groups;

// Shapes (fixed): B=4, N=256, F=6, H=128, D=256, B*N=1024
// All tensors fp32. out = concat(adj_pred [4,256,256], feat_pred [4,256,6]).
// This round: single cooperative mega-kernel (8 grid syncs replace 8 launch
// boundaries). Math identical to verified Round-1 code. 9-launch fallback
// retained if cooperative launch is rejected.

typedef float v4f __attribute__((ext_vector_type(4)));
typedef short v8s __attribute__((ext_vector_type(8)));

__device__ __forceinline__ unsigned short f2bs(float f) {
    union { float f; unsigned int u; } v;
    v.f = f;
    return (unsigned short)((v.u + 0x7fffu + ((v.u >> 16) & 1u)) >> 16);
}

// ---- L0 unit: role-split prologue ----
__device__ __forceinline__ void pre_unit(int blk, int tid,
        const float* x, const float* W1, const float* adj, const float* e2w,
        float* buf, float* dg, unsigned short* bfr_g, float* st, float* ss) {
    if (blk < 512) {
        int idx = blk * 256 + tid;
        int m = idx >> 7, n = idx & 127;
        float s = 0.f;
        for (int k = 0; k < 6; k++) s += x[m * 6 + k] * W1[k * 128 + n];
        buf[idx] = s;
    } else if (blk < 768) {
        int row = (blk - 512) * 4 + (tid >> 6);
        int lane = tid & 63;
        const float* ap = adj + (long)row * 256;
        ss[tid] = ap[lane] + ap[lane + 64] + ap[lane + 128] + ap[lane + 192];
        __syncthreads();
        for (int o = 32; o > 0; o >>= 1) {
            if (lane < o) ss[tid] += ss[tid + o];
            __syncthreads();
        }
        if (lane == 0) {
            float t = ss[tid] + 1.f;
            if (t < 1.f) t = 1.f;
            dg[row] = rsqrtf(t);
        }
    } else {
        for (int s = tid; s < 8192; s += 256) {
            int k = s >> 6, n = s & 63;
            int kc = k >> 5, q = (k & 31) >> 3, t = k & 7;
            int nt = n >> 4, c2 = n & 15;
            bfr_g[(((nt * 4 + kc) * 64) + q * 16 + c2) * 8 + t] = f2bs(e2w[s]);
        }
        st[tid] = 0.f;
        st[256 + tid] = 0.f;
    }
}

// ---- tiled GEMM, 16x32 tile, compile-time K, reg-staged loads ----
template <int K>
__device__ __forceinline__ void dev_tile(
        int t, const float* A, const float* B, const float* bias,
        const float* dgA, float* anOut,
        const float* stat, const float* g, const float* beta,
        float* ostat, float* C,
        int N, int relu,
        int sA, int sB, int sC, int tiles_n, int tiles_m,
        float* smem) {
    constexpr int strideA = K + 4;
    constexpr int NCH = K / 16;
    float* As = smem;                 // [16][K+4]  <= 4160
    float* Bs = smem + 4160;          // [K][32]    <= 8192
    int tid = threadIdx.x;
    int n2 = tid & 15, ml = tid >> 4;
    int bx = t % tiles_n;
    int tmp = t / tiles_n;
    int by = tmp % tiles_m;
    int bz = tmp / tiles_m;
    int m0 = by * 16, n0 = bx * 32;
    const float* Ab = A + (long)bz * sA;
    const float* Bb = B + (long)bz * sB;
    float* Cb = C + (long)bz * sC;
    const float* dgb = (dgA != 0) ? (dgA + bz * 256) : 0;

    int kk = tid & 15, mm = tid >> 4;
    int nb = tid & 31, kb = tid >> 5;

    // phase 1: issue ALL global loads into registers (one round trip)
    float b0_r[NCH], b1_r[NCH], a_r[NCH];
    const float* Arow = Ab + (long)(m0 + mm) * K;
    #pragma unroll
    for (int i = 0; i < NCH; i++) {
        a_r[i]  = Arow[i * 16 + kk];
        b0_r[i] = Bb[(long)(i * 16 + kb) * N + n0 + nb];
        b1_r[i] = Bb[(long)(i * 16 + kb + 8) * N + n0 + nb];
    }

    // phase 2: per-path A processing + LDS writes
    if (dgA != 0) {
        float di = dgb[m0 + mm];
        float d_r[NCH];
        #pragma unroll
        for (int i = 0; i < NCH; i++) d_r[i] = dgb[i * 16 + kk];
        #pragma unroll
        for (int i = 0; i < NCH; i++) {
            int kg = i * 16 + kk;
            float v = a_r[i];
            if (m0 + mm == kg) v += 1.f;
            v = di * v * d_r[i];
            if (anOut != 0 && bx == 0)
                anOut[bz * 65536 + (m0 + mm) * 256 + kg] = v;
            As[mm * strideA + kg] = v;
        }
    } else if (stat != 0) {
        float s_r[NCH], q_r[NCH], g_r[NCH], be_r[NCH];
        #pragma unroll
        for (int i = 0; i < NCH; i++) {
            int kg = i * 16 + kk;
            s_r[i]  = stat[kg];
            q_r[i]  = stat[128 + kg];
            g_r[i]  = g[kg];
            be_r[i] = beta[kg];
        }
        #pragma unroll
        for (int i = 0; i < NCH; i++) {
            int kg = i * 16 + kk;
            float mu = s_r[i] * (1.f / 1024.f);
            float vr = q_r[i] * (1.f / 1024.f) - mu * mu;
            float sc = rsqrtf(vr + 1e-5f) * g_r[i];
            float v = (a_r[i] - mu) * sc + be_r[i];
            if (v < 0.f) v = 0.f;
            As[mm * strideA + kg] = v;
        }
    } else {
        #pragma unroll
        for (int i = 0; i < NCH; i++)
            As[mm * strideA + i * 16 + kk] = a_r[i];
    }
    #pragma unroll
    for (int i = 0; i < NCH; i++) {
        Bs[(i * 16 + kb) * 32 + nb] = b0_r[i];
        Bs[(i * 16 + kb + 8) * 32 + nb] = b1_r[i];
    }
    __syncthreads();

    // inner product: fully unrolled, split accumulators
    float c0a = 0.f, c0b = 0.f, c1a = 0.f, c1b = 0.f;
    const float* arow = As + ml * strideA;
    const float* bcol = Bs + n2 * 2;
    #pragma unroll
    for (int q0 = 0; q0 < K; q0 += 4) {
        float4 av = *(const float4*)(arow + q0);
        float2 b0 = *(const float2*)(bcol + (q0 + 0) * 32);
        float2 b1 = *(const float2*)(bcol + (q0 + 1) * 32);
        float2 b2 = *(const float2*)(bcol + (q0 + 2) * 32);
        float2 b3 = *(const float2*)(bcol + (q0 + 3) * 32);
        c0a += av.x * b0.x; c1a += av.x * b0.y;
        c0b += av.y * b1.x; c1b += av.y * b1.y;
        c0a += av.z * b2.x; c1a += av.z * b2.y;
        c0b += av.w * b3.x; c1b += av.w * b3.y;
    }
    float c0 = c0a + c0b, c1 = c1a + c1b;
    int mRow = m0 + ml, nn = n0 + n2 * 2;
    if (bias != 0) { c0 += bias[nn]; c1 += bias[nn + 1]; }
    if (relu) {
        if (c0 < 0.f) c0 = 0.f;
        if (c1 < 0.f) c1 = 0.f;
    }
    Cb[(long)mRow * N + nn] = c0;
    Cb[(long)mRow * N + nn + 1] = c1;

    if (ostat != 0) {
        float* sred = smem;
        float* qred = smem + 544;
        __syncthreads();
        sred[(n2 * 2) * 17 + ml] = c0;
        sred[(n2 * 2 + 1) * 17 + ml] = c1;
        qred[(n2 * 2) * 17 + ml] = c0 * c0;
        qred[(n2 * 2 + 1) * 17 + ml] = c1 * c1;
        __syncthreads();
        if (tid < 32) {
            float s = 0.f, q = 0.f;
            for (int u = 0; u < 16; u++) {
                s += sred[tid * 17 + u];
                q += qred[tid * 17 + u];
            }
            atomicAdd(&ostat[n0 + tid], s);
            atomicAdd(&ostat[128 + n0 + tid], q);
        }
    }
}

// ---- L8 unit: {MFMA pair decoder} or {feature f2/f3} ----
__device__ __forceinline__ void dec_unit(int blk,
        const float* hi, const float* hj, const float* e1b,
        const unsigned short* bfr_g, const float* e2b,
        const float* e3w, const float* e3b,
        const float* f1, const float* f2w, const float* f2b_,
        const float* f3w, const float* f3b,
        float* lg, float* out, float* smem) {
    int tid = threadIdx.x;
    if (blk < 1024) {
        float* red = smem;                           // [256][17] = 4352
        float* pre_sh = smem + 4352;                 // 128
        int lane = tid & 63, wv = tid >> 6;
        int col = lane & 15, quad = lane >> 4;
        int bi = blk, b = bi >> 8;
        if (tid < 128) pre_sh[tid] = hi[bi * 128 + tid] + e1b[tid];
        __syncthreads();
        float e2bv[4], e3wv[4];
        for (int nt = 0; nt < 4; nt++) {
            e2bv[nt] = e2b[nt * 16 + col];
            e3wv[nt] = e3w[nt * 16 + col];
        }
        const float* hjb = hj + b * 32768;
        #pragma unroll 1
        for (int ms = 0; ms < 4; ms++) {
            v4f acc[4];
            for (int nt = 0; nt < 4; nt++) {
                v4f z = {0.f, 0.f, 0.f, 0.f};
                acc[nt] = z;
            }
            int j = wv * 64 + ms * 16 + col;
            const float* rowp = hjb + j * 128 + quad * 8;
            #pragma unroll 1
            for (int kc = 0; kc < 4; kc++) {
                const float* pp = pre_sh + kc * 32 + quad * 8;
                const float* hp = rowp + kc * 32;
                v8s af;
                #pragma unroll
                for (int t = 0; t < 8; t++) {
                    float p = pp[t] + hp[t];
                    p = (p > 0.f) ? p : 0.f;
                    af[t] = (short)f2bs(p);
                }
                #pragma unroll
                for (int nt = 0; nt < 4; nt++) {
                    v8s bf = *(const v8s*)&bfr_g[(((nt * 4 + kc) * 64) + lane) * 8];
                    acc[nt] = __builtin_amdgcn_mfma_f32_16x16x32_bf16(
                        af, bf, acc[nt], 0, 0, 0);
                }
            }
            #pragma unroll
            for (int r = 0; r < 4; r++) {
                float s = 0.f;
                #pragma unroll
                for (int nt = 0; nt < 4; nt++) {
                    float v = acc[nt][r] + e2bv[nt];
                    if (v > 0.f) s += v * e3wv[nt];
                }
                red[(wv * 64 + ms * 16 + quad * 4 + r) * 17 + col] = s;
            }
        }
        __syncthreads();
        float s = e3b[0];
        for (int c = 0; c < 16; c++) s += red[tid * 17 + c];
        lg[bi * 256 + tid] = s;
    } else {
        float* f2row = smem;                         // 512 floats
        int r0 = (blk - 1024) * 4;
        for (int p = 0; p < 2; p++) {
            int idx = tid + p * 256;
            int r = r0 + (idx >> 7), n = idx & 127;
            const float* f1r = f1 + (long)r * 128;
            float s0 = 0.f, s1 = 0.f, s2 = 0.f, s3 = 0.f;
            #pragma unroll
            for (int k = 0; k < 128; k += 4) {
                float4 fv = *(const float4*)(f1r + k);
                s0 += fv.x * f2w[(k + 0) * 128 + n];
                s1 += fv.y * f2w[(k + 1) * 128 + n];
                s2 += fv.z * f2w[(k + 2) * 128 + n];
                s3 += fv.w * f2w[(k + 3) * 128 + n];
            }
            float s = f2b_[n] + ((s0 + s1) + (s2 + s3));
            if (s < 0.f) s = 0.f;
            f2row[idx] = s;
        }
        __syncthreads();
        if (tid < 24) {
            int r = tid / 6, c = tid % 6;
            float s = f3b[c];
            const float* fr = f2row + r * 128;
            for (int k = 0; k < 128; k++) s += fr[k] * f3w[k * 6 + c];
            out[262144 + (r0 + r) * 6 + c] = s;
        }
    }
}

// ---- L9 unit: tiled symmetrize + sigmoid ----
__device__ __forceinline__ void symsig_unit(int blk, const float* lg,
                                            float* out, float* smem) {
    float* Ta = smem;            // 32*33
    float* Tb = smem + 32 * 33;  // 32*33
    int tid = threadIdx.x;
    int b = blk / 36;
    int t = blk % 36;
    int ti = 0, rem = t;
    while (rem >= 8 - ti) { rem -= 8 - ti; ti++; }
    int tj = ti + rem;
    int i0 = ti * 32, j0 = tj * 32;
    const float* lgb = lg + b * 65536;
    for (int p = 0; p < 4; p++) {
        int idx = p * 256 + tid;
        int r = idx >> 5, c = idx & 31;
        Ta[r * 33 + c] = lgb[(i0 + r) * 256 + j0 + c];
        Tb[r * 33 + c] = lgb[(j0 + r) * 256 + i0 + c];
    }
    __syncthreads();
    float* ob = out + b * 65536;
    for (int p = 0; p < 4; p++) {
        int idx = p * 256 + tid;
        int r = idx >> 5, c = idx & 31;
        float v1 = 0.5f * (Ta[r * 33 + c] + Tb[c * 33 + r]);
        ob[(i0 + r) * 256 + j0 + c] = 1.f / (1.f + expf(-v1));
        float v2 = 0.5f * (Tb[r * 33 + c] + Ta[c * 33 + r]);
        ob[(j0 + r) * 256 + i0 + c] = 1.f / (1.f + expf(-v2));
    }
}

// ================= cooperative mega-kernel =================
struct P {
    const float *x, *adj, *W1, *b1, *W2, *b2, *W3, *b3, *g1, *be1, *g2, *be2;
    const float *e1w, *e1b, *e2w, *e2b, *e3w, *e3b;
    const float *f1w, *f1b, *f2w, *f2b, *f3w, *f3b;
    float* out;
    float *st1, *st2, *dg;
    unsigned short* bfr_g;
    float *An, *buf, *hb, *lg, *h1, *h2, *hi, *hj;
};

__global__ __launch_bounds__(256, 2) void k_fused(P p) {
    __shared__ float smem[12352];
    cg::grid_group grid = cg::this_grid();
    int bid = blockIdx.x, tid = threadIdx.x;

    // S0: prologue (769 units)
    for (int u = bid; u < 769; u += 512) {
        pre_unit(u, tid, p.x, p.W1, p.adj, p.e2w, p.buf, p.dg, p.bfr_g, p.st1, smem);
        __syncthreads();
    }
    grid.sync();
    // S1 (L2): h1 = norm(adj)@buf + b1 (+stats->st1); An materialized
    if (bid < 256)
        dev_tile<256>(bid, p.adj, p.buf, p.b1, p.dg, p.An, 0, 0, 0, p.st1, p.h1,
                      128, 0, 65536, 32768, 32768, 4, 16, smem);
    grid.sync();
    // S2 (L3): buf = BN(h1)@W2
    if (bid < 256)
        dev_tile<128>(bid, p.h1, p.W2, 0, 0, 0, p.st1, p.g1, p.be1, 0, p.buf,
                      128, 0, 0, 0, 0, 4, 64, smem);
    grid.sync();
    // S3 (L4): h2 = An@buf + b2 (+stats->st2)
    if (bid < 256)
        dev_tile<256>(bid, p.An, p.buf, p.b2, 0, 0, 0, 0, 0, p.st2, p.h2,
                      128, 0, 65536, 32768, 32768, 4, 16, smem);
    grid.sync();
    // S4 (L5): buf = BN(h2)@W3   (512 units)
    dev_tile<128>(bid, p.h2, p.W3, 0, 0, 0, p.st2, p.g2, p.be2, 0, p.buf,
                  256, 0, 0, 0, 0, 8, 64, smem);
    grid.sync();
    // S5 (L6): hb = relu(An@buf + b3)   (512 units)
    dev_tile<256>(bid, p.An, p.buf, p.b3, 0, 0, 0, 0, 0, 0, p.hb,
                  256, 1, 65536, 65536, 65536, 8, 16, smem);
    grid.sync();
    // S6 (L7): hi/hj (batch-2) + f1 (768 units)
    for (int u = bid; u < 768; u += 512) {
        if (u < 512)
            dev_tile<256>(u, p.hb, p.e1w, 0, 0, 0, 0, 0, 0, 0, p.hi,
                          128, 0, 0, 32768, 131072, 4, 64, smem);
        else
            dev_tile<256>(u - 512, p.hb, p.f1w, p.f1b, 0, 0, 0, 0, 0, 0, p.h1,
                          128, 1, 0, 0, 0, 4, 64, smem);
        __syncthreads();
    }
    grid.sync();
    // S7 (L8): decoder + feature f2/f3 (1280 units)
    for (int u = bid; u < 1280; u += 512) {
        dec_unit(u, p.hi, p.hj, p.e1b, p.bfr_g, p.e2b, p.e3w, p.e3b,
                 p.h1, p.f2w, p.f2b, p.f3w, p.f3b, p.lg, p.out, smem);
        __syncthreads();
    }
    grid.sync();
    // S8 (L9): symmetrize + sigmoid (144 units)
    if (bid < 144)
        symsig_unit(bid, p.lg, p.out, smem);
}

// ================= fallback standalone kernels =================
__global__ void k_pre(const float* x, const float* W1, const float* adj,
                      const float* e2w, float* buf, float* dg,
                      unsigned short* bfr_g, float* st) {
    __shared__ float ss[256];
    pre_unit(blockIdx.x, threadIdx.x, x, W1, adj, e2w, buf, dg, bfr_g, st, ss);
}

template <int K>
__global__ __launch_bounds__(256, 3) void k_tgemm(
        const float* A, const float* B, const float* bias,
        const float* dgA, float* anOut,
        const float* stat, const float* g, const float* beta,
        float* ostat, float* C,
        int N, int relu,
        int sA, int sB, int sC, int tiles_n, int tiles_m) {
    __shared__ float smem[12352];
    dev_tile<K>(blockIdx.x, A, B, bias, dgA, anOut, stat, g, beta, ostat, C,
                N, relu, sA, sB, sC, tiles_n, tiles_m, smem);
}

__global__ __launch_bounds__(256, 3) void k_g67(
        const float* hb, const float* e1w, float* hi,
        const float* f1w, const float* f1b, float* f1) {
    __shared__ float smem[12352];
    int t = blockIdx.x;
    if (t < 512) {
        dev_tile<256>(t, hb, e1w, 0, 0, 0, 0, 0, 0, 0, hi,
                      128, 0, 0, 32768, 131072, 4, 64, smem);
    } else {
        dev_tile<256>(t - 512, hb, f1w, f1b, 0, 0, 0, 0, 0, 0, f1,
                      128, 1, 0, 0, 0, 4, 64, smem);
    }
}

__global__ void k_decf(const float* hi, const float* hj, const float* e1b,
                       const unsigned short* bfr_g, const float* e2b,
                       const float* e3w, const float* e3b,
                       const float* f1, const float* f2w, const float* f2b_,
                       const float* f3w, const float* f3b,
                       float* lg, float* out) {
    __shared__ float smem[4608];
    dec_unit(blockIdx.x, hi, hj, e1b, bfr_g, e2b, e3w, e3b,
             f1, f2w, f2b_, f3w, f3b, lg, out, smem);
}

__global__ void k_symsig(const float* lg, float* out) {
    __shared__ float smem[2 * 32 * 33];
    symsig_unit(blockIdx.x, lg, out, smem);
}

extern "C" void kernel_launch(void* const* d_in, const int* in_sizes, int n_in,
                              void* d_out, int out_size, void* d_ws, size_t ws_size,
                              hipStream_t stream) {
    const float* x   = (const float*)d_in[0];
    const float* adj = (const float*)d_in[1];
    const float* W1  = (const float*)d_in[2];
    const float* b1  = (const float*)d_in[3];
    const float* W2  = (const float*)d_in[4];
    const float* b2  = (const float*)d_in[5];
    const float* W3  = (const float*)d_in[6];
    const float* b3  = (const float*)d_in[7];
    const float* g1  = (const float*)d_in[8];
    const float* be1 = (const float*)d_in[9];
    const float* g2  = (const float*)d_in[10];
    const float* be2 = (const float*)d_in[11];
    const float* e1w = (const float*)d_in[12];
    const float* e1b = (const float*)d_in[13];
    const float* e2w = (const float*)d_in[14];
    const float* e2b = (const float*)d_in[15];
    const float* e3w = (const float*)d_in[16];
    const float* e3b = (const float*)d_in[17];
    const float* f1w = (const float*)d_in[18];
    const float* f1b = (const float*)d_in[19];
    const float* f2w = (const float*)d_in[20];
    const float* f2b_ = (const float*)d_in[21];
    const float* f3w = (const float*)d_in[22];
    const float* f3b = (const float*)d_in[23];

    float* out = (float*)d_out;

    if (ws_size < (size_t)1600000 * 4) {
        hipMemsetAsync(d_out, 0x60, 4096, stream);   // diagnostic
        return;
    }
    float* ws = (float*)d_ws;
    float* st1 = ws;                        // 256 (zeroed in pre)
    float* st2 = ws + 256;                  // 256 (zeroed in pre)
    float* dg  = ws + 512;                  // 1024
    unsigned short* bfr_g = (unsigned short*)(ws + 1536);   // 8192 us
    float* An  = ws + 5632;                 // 262144 (materialized by S1)
    float* buf = An + 262144;
    float* hb  = buf + 262144;
    float* lg  = hb + 262144;
    float* h1  = lg + 262144;               // 131072 (later reused as f1)
    float* h2  = h1 + 131072;
    float* hi  = h2 + 131072;
    float* hj  = hi + 131072;               // contiguous after hi (batch-2)

    P prm;
    prm.x = x; prm.adj = adj; prm.W1 = W1; prm.b1 = b1; prm.W2 = W2; prm.b2 = b2;
    prm.W3 = W3; prm.b3 = b3; prm.g1 = g1; prm.be1 = be1; prm.g2 = g2; prm.be2 = be2;
    prm.e1w = e1w; prm.e1b = e1b; prm.e2w = e2w; prm.e2b = e2b; prm.e3w = e3w; prm.e3b = e3b;
    prm.f1w = f1w; prm.f1b = f1b; prm.f2w = f2w; prm.f2b = f2b_; prm.f3w = f3w; prm.f3b = f3b;
    prm.out = out;
    prm.st1 = st1; prm.st2 = st2; prm.dg = dg; prm.bfr_g = bfr_g;
    prm.An = An; prm.buf = buf; prm.hb = hb; prm.lg = lg;
    prm.h1 = h1; prm.h2 = h2; prm.hi = hi; prm.hj = hj;

    void* args[] = { (void*)&prm };
    hipError_t err = hipLaunchCooperativeKernel((const void*)k_fused,
                                                dim3(512), dim3(256),
                                                args, 0, stream);
    if (err == hipSuccess) return;
    (void)hipGetLastError();   // clear sticky error, fall back

    // ---- fallback: verified 9-launch schedule ----
    k_pre<<<769, 256, 0, stream>>>(x, W1, adj, e2w, buf, dg, bfr_g, st1);
    k_tgemm<256><<<256, 256, 0, stream>>>(adj, buf, b1, dg, An, 0, 0, 0, st1, h1,
                                          128, 0, 65536, 32768, 32768, 4, 16);
    k_tgemm<128><<<256, 256, 0, stream>>>(h1, W2, 0, 0, 0, st1, g1, be1, 0, buf,
                                          128, 0, 0, 0, 0, 4, 64);
    k_tgemm<256><<<256, 256, 0, stream>>>(An, buf, b2, 0, 0, 0, 0, 0, st2, h2,
                                          128, 0, 65536, 32768, 32768, 4, 16);
    k_tgemm<128><<<512, 256, 0, stream>>>(h2, W3, 0, 0, 0, st2, g2, be2, 0, buf,
                                          256, 0, 0, 0, 0, 8, 64);
    k_tgemm<256><<<512, 256, 0, stream>>>(An, buf, b3, 0, 0, 0, 0, 0, 0, hb,
                                          256, 1, 65536, 65536, 65536, 8, 16);
    k_g67<<<768, 256, 0, stream>>>(hb, e1w, hi, f1w, f1b, h1);
    k_decf<<<1280, 256, 0, stream>>>(hi, hj, e1b, bfr_g, e2b, e3w, e3b,
                                     h1, f2w, f2b_, f3w, f3b, lg, out);
    k_symsig<<<144, 256, 0, stream>>>(lg, out);
}

// Round 3
// 377.261 us; speedup vs baseline: 1.7191x; 1.7191x over previous
//
#include <hip/hip_runtime.h>

// Shapes (fixed): B=4, N=256, F=6, H=128, D=256, B*N=1024
// All tensors fp32. out = concat(adj_pred [4,256,256], feat_pred [4,256,6]).
// This round: fused cooperative kernel with HAND-ROLLED grid barrier
// (cg::grid.sync measured ~65us/sync in R2; target ~4us/sync).
// Math identical to verified Round-1 code. 9-launch fallback retained.

typedef float v4f __attribute__((ext_vector_type(4)));
typedef short v8s __attribute__((ext_vector_type(8)));

__device__ __forceinline__ unsigned short f2bs(float f) {
    union { float f; unsigned int u; } v;
    v.f = f;
    return (unsigned short)((v.u + 0x7fffu + ((v.u >> 16) & 1u)) >> 16);
}

// ---- hand-rolled grid barrier (512 blocks, monotonic phases) ----
// bars layout (uint idx): sub-counters at i*32 (i=0..7, 128B apart),
// root at 256, flag at 288. All zeroed by hipMemsetAsync before launch.
__device__ __forceinline__ void gbar(unsigned* bars, int phase) {
    __syncthreads();
    if (threadIdx.x == 0) {
        __builtin_amdgcn_fence(__ATOMIC_RELEASE, "agent");   // publish stage writes (L2 wb)
        unsigned* sub = bars + (blockIdx.x & 7) * 32;
        unsigned a = __hip_atomic_fetch_add(sub, 1u, __ATOMIC_RELAXED,
                                            __HIP_MEMORY_SCOPE_AGENT);
        if (a == (unsigned)(phase * 64 - 1)) {               // last of 64 on this sub
            unsigned r = __hip_atomic_fetch_add(bars + 256, 1u, __ATOMIC_RELAXED,
                                                __HIP_MEMORY_SCOPE_AGENT);
            if (r == (unsigned)(phase * 8 - 1))              // last sub overall
                __hip_atomic_store(bars + 288, (unsigned)phase, __ATOMIC_RELAXED,
                                   __HIP_MEMORY_SCOPE_AGENT);
        }
        while (__hip_atomic_load(bars + 288, __ATOMIC_RELAXED,
                                 __HIP_MEMORY_SCOPE_AGENT) < (unsigned)phase)
            __builtin_amdgcn_s_sleep(8);
        __builtin_amdgcn_fence(__ATOMIC_ACQUIRE, "agent");   // invalidate stale caches
    }
    __syncthreads();
}

// ---- L0 unit: role-split prologue ----
__device__ __forceinline__ void pre_unit(int blk, int tid,
        const float* x, const float* W1, const float* adj, const float* e2w,
        float* buf, float* dg, unsigned short* bfr_g, float* st, float* ss) {
    if (blk < 512) {
        int idx = blk * 256 + tid;
        int m = idx >> 7, n = idx & 127;
        float s = 0.f;
        for (int k = 0; k < 6; k++) s += x[m * 6 + k] * W1[k * 128 + n];
        buf[idx] = s;
    } else if (blk < 768) {
        int row = (blk - 512) * 4 + (tid >> 6);
        int lane = tid & 63;
        const float* ap = adj + (long)row * 256;
        ss[tid] = ap[lane] + ap[lane + 64] + ap[lane + 128] + ap[lane + 192];
        __syncthreads();
        for (int o = 32; o > 0; o >>= 1) {
            if (lane < o) ss[tid] += ss[tid + o];
            __syncthreads();
        }
        if (lane == 0) {
            float t = ss[tid] + 1.f;
            if (t < 1.f) t = 1.f;
            dg[row] = rsqrtf(t);
        }
    } else {
        for (int s = tid; s < 8192; s += 256) {
            int k = s >> 6, n = s & 63;
            int kc = k >> 5, q = (k & 31) >> 3, t = k & 7;
            int nt = n >> 4, c2 = n & 15;
            bfr_g[(((nt * 4 + kc) * 64) + q * 16 + c2) * 8 + t] = f2bs(e2w[s]);
        }
        st[tid] = 0.f;
        st[256 + tid] = 0.f;
    }
}

// ---- tiled GEMM, 16x32 tile, compile-time K, reg-staged loads ----
template <int K>
__device__ __forceinline__ void dev_tile(
        int t, const float* A, const float* B, const float* bias,
        const float* dgA, float* anOut,
        const float* stat, const float* g, const float* beta,
        float* ostat, float* C,
        int N, int relu,
        int sA, int sB, int sC, int tiles_n, int tiles_m,
        float* smem) {
    constexpr int strideA = K + 4;
    constexpr int NCH = K / 16;
    float* As = smem;                 // [16][K+4]  <= 4160
    float* Bs = smem + 4160;          // [K][32]    <= 8192
    int tid = threadIdx.x;
    int n2 = tid & 15, ml = tid >> 4;
    int bx = t % tiles_n;
    int tmp = t / tiles_n;
    int by = tmp % tiles_m;
    int bz = tmp / tiles_m;
    int m0 = by * 16, n0 = bx * 32;
    const float* Ab = A + (long)bz * sA;
    const float* Bb = B + (long)bz * sB;
    float* Cb = C + (long)bz * sC;
    const float* dgb = (dgA != 0) ? (dgA + bz * 256) : 0;

    int kk = tid & 15, mm = tid >> 4;
    int nb = tid & 31, kb = tid >> 5;

    // phase 1: issue ALL global loads into registers (one round trip)
    float b0_r[NCH], b1_r[NCH], a_r[NCH];
    const float* Arow = Ab + (long)(m0 + mm) * K;
    #pragma unroll
    for (int i = 0; i < NCH; i++) {
        a_r[i]  = Arow[i * 16 + kk];
        b0_r[i] = Bb[(long)(i * 16 + kb) * N + n0 + nb];
        b1_r[i] = Bb[(long)(i * 16 + kb + 8) * N + n0 + nb];
    }

    // phase 2: per-path A processing + LDS writes
    if (dgA != 0) {
        float di = dgb[m0 + mm];
        float d_r[NCH];
        #pragma unroll
        for (int i = 0; i < NCH; i++) d_r[i] = dgb[i * 16 + kk];
        #pragma unroll
        for (int i = 0; i < NCH; i++) {
            int kg = i * 16 + kk;
            float v = a_r[i];
            if (m0 + mm == kg) v += 1.f;
            v = di * v * d_r[i];
            if (anOut != 0 && bx == 0)
                anOut[bz * 65536 + (m0 + mm) * 256 + kg] = v;
            As[mm * strideA + kg] = v;
        }
    } else if (stat != 0) {
        float s_r[NCH], q_r[NCH], g_r[NCH], be_r[NCH];
        #pragma unroll
        for (int i = 0; i < NCH; i++) {
            int kg = i * 16 + kk;
            s_r[i]  = stat[kg];
            q_r[i]  = stat[128 + kg];
            g_r[i]  = g[kg];
            be_r[i] = beta[kg];
        }
        #pragma unroll
        for (int i = 0; i < NCH; i++) {
            int kg = i * 16 + kk;
            float mu = s_r[i] * (1.f / 1024.f);
            float vr = q_r[i] * (1.f / 1024.f) - mu * mu;
            float sc = rsqrtf(vr + 1e-5f) * g_r[i];
            float v = (a_r[i] - mu) * sc + be_r[i];
            if (v < 0.f) v = 0.f;
            As[mm * strideA + kg] = v;
        }
    } else {
        #pragma unroll
        for (int i = 0; i < NCH; i++)
            As[mm * strideA + i * 16 + kk] = a_r[i];
    }
    #pragma unroll
    for (int i = 0; i < NCH; i++) {
        Bs[(i * 16 + kb) * 32 + nb] = b0_r[i];
        Bs[(i * 16 + kb + 8) * 32 + nb] = b1_r[i];
    }
    __syncthreads();

    // inner product: fully unrolled, split accumulators
    float c0a = 0.f, c0b = 0.f, c1a = 0.f, c1b = 0.f;
    const float* arow = As + ml * strideA;
    const float* bcol = Bs + n2 * 2;
    #pragma unroll
    for (int q0 = 0; q0 < K; q0 += 4) {
        float4 av = *(const float4*)(arow + q0);
        float2 b0 = *(const float2*)(bcol + (q0 + 0) * 32);
        float2 b1 = *(const float2*)(bcol + (q0 + 1) * 32);
        float2 b2 = *(const float2*)(bcol + (q0 + 2) * 32);
        float2 b3 = *(const float2*)(bcol + (q0 + 3) * 32);
        c0a += av.x * b0.x; c1a += av.x * b0.y;
        c0b += av.y * b1.x; c1b += av.y * b1.y;
        c0a += av.z * b2.x; c1a += av.z * b2.y;
        c0b += av.w * b3.x; c1b += av.w * b3.y;
    }
    float c0 = c0a + c0b, c1 = c1a + c1b;
    int mRow = m0 + ml, nn = n0 + n2 * 2;
    if (bias != 0) { c0 += bias[nn]; c1 += bias[nn + 1]; }
    if (relu) {
        if (c0 < 0.f) c0 = 0.f;
        if (c1 < 0.f) c1 = 0.f;
    }
    Cb[(long)mRow * N + nn] = c0;
    Cb[(long)mRow * N + nn + 1] = c1;

    if (ostat != 0) {
        float* sred = smem;
        float* qred = smem + 544;
        __syncthreads();
        sred[(n2 * 2) * 17 + ml] = c0;
        sred[(n2 * 2 + 1) * 17 + ml] = c1;
        qred[(n2 * 2) * 17 + ml] = c0 * c0;
        qred[(n2 * 2 + 1) * 17 + ml] = c1 * c1;
        __syncthreads();
        if (tid < 32) {
            float s = 0.f, q = 0.f;
            for (int u = 0; u < 16; u++) {
                s += sred[tid * 17 + u];
                q += qred[tid * 17 + u];
            }
            atomicAdd(&ostat[n0 + tid], s);
            atomicAdd(&ostat[128 + n0 + tid], q);
        }
    }
}

// ---- L8 unit: {MFMA pair decoder} or {feature f2/f3} ----
__device__ __forceinline__ void dec_unit(int blk,
        const float* hi, const float* hj, const float* e1b,
        const unsigned short* bfr_g, const float* e2b,
        const float* e3w, const float* e3b,
        const float* f1, const float* f2w, const float* f2b_,
        const float* f3w, const float* f3b,
        float* lg, float* out, float* smem) {
    int tid = threadIdx.x;
    if (blk < 1024) {
        float* red = smem;                           // [256][17] = 4352
        float* pre_sh = smem + 4352;                 // 128
        int lane = tid & 63, wv = tid >> 6;
        int col = lane & 15, quad = lane >> 4;
        int bi = blk, b = bi >> 8;
        if (tid < 128) pre_sh[tid] = hi[bi * 128 + tid] + e1b[tid];
        __syncthreads();
        float e2bv[4], e3wv[4];
        for (int nt = 0; nt < 4; nt++) {
            e2bv[nt] = e2b[nt * 16 + col];
            e3wv[nt] = e3w[nt * 16 + col];
        }
        const float* hjb = hj + b * 32768;
        #pragma unroll 1
        for (int ms = 0; ms < 4; ms++) {
            v4f acc[4];
            for (int nt = 0; nt < 4; nt++) {
                v4f z = {0.f, 0.f, 0.f, 0.f};
                acc[nt] = z;
            }
            int j = wv * 64 + ms * 16 + col;
            const float* rowp = hjb + j * 128 + quad * 8;
            #pragma unroll 1
            for (int kc = 0; kc < 4; kc++) {
                const float* pp = pre_sh + kc * 32 + quad * 8;
                const float* hp = rowp + kc * 32;
                v8s af;
                #pragma unroll
                for (int t = 0; t < 8; t++) {
                    float p = pp[t] + hp[t];
                    p = (p > 0.f) ? p : 0.f;
                    af[t] = (short)f2bs(p);
                }
                #pragma unroll
                for (int nt = 0; nt < 4; nt++) {
                    v8s bf = *(const v8s*)&bfr_g[(((nt * 4 + kc) * 64) + lane) * 8];
                    acc[nt] = __builtin_amdgcn_mfma_f32_16x16x32_bf16(
                        af, bf, acc[nt], 0, 0, 0);
                }
            }
            #pragma unroll
            for (int r = 0; r < 4; r++) {
                float s = 0.f;
                #pragma unroll
                for (int nt = 0; nt < 4; nt++) {
                    float v = acc[nt][r] + e2bv[nt];
                    if (v > 0.f) s += v * e3wv[nt];
                }
                red[(wv * 64 + ms * 16 + quad * 4 + r) * 17 + col] = s;
            }
        }
        __syncthreads();
        float s = e3b[0];
        for (int c = 0; c < 16; c++) s += red[tid * 17 + c];
        lg[bi * 256 + tid] = s;
    } else {
        float* f2row = smem;                         // 512 floats
        int r0 = (blk - 1024) * 4;
        for (int p = 0; p < 2; p++) {
            int idx = tid + p * 256;
            int r = r0 + (idx >> 7), n = idx & 127;
            const float* f1r = f1 + (long)r * 128;
            float s0 = 0.f, s1 = 0.f, s2 = 0.f, s3 = 0.f;
            #pragma unroll
            for (int k = 0; k < 128; k += 4) {
                float4 fv = *(const float4*)(f1r + k);
                s0 += fv.x * f2w[(k + 0) * 128 + n];
                s1 += fv.y * f2w[(k + 1) * 128 + n];
                s2 += fv.z * f2w[(k + 2) * 128 + n];
                s3 += fv.w * f2w[(k + 3) * 128 + n];
            }
            float s = f2b_[n] + ((s0 + s1) + (s2 + s3));
            if (s < 0.f) s = 0.f;
            f2row[idx] = s;
        }
        __syncthreads();
        if (tid < 24) {
            int r = tid / 6, c = tid % 6;
            float s = f3b[c];
            const float* fr = f2row + r * 128;
            for (int k = 0; k < 128; k++) s += fr[k] * f3w[k * 6 + c];
            out[262144 + (r0 + r) * 6 + c] = s;
        }
    }
}

// ---- L9 unit: tiled symmetrize + sigmoid ----
__device__ __forceinline__ void symsig_unit(int blk, const float* lg,
                                            float* out, float* smem) {
    float* Ta = smem;            // 32*33
    float* Tb = smem + 32 * 33;  // 32*33
    int tid = threadIdx.x;
    int b = blk / 36;
    int t = blk % 36;
    int ti = 0, rem = t;
    while (rem >= 8 - ti) { rem -= 8 - ti; ti++; }
    int tj = ti + rem;
    int i0 = ti * 32, j0 = tj * 32;
    const float* lgb = lg + b * 65536;
    for (int p = 0; p < 4; p++) {
        int idx = p * 256 + tid;
        int r = idx >> 5, c = idx & 31;
        Ta[r * 33 + c] = lgb[(i0 + r) * 256 + j0 + c];
        Tb[r * 33 + c] = lgb[(j0 + r) * 256 + i0 + c];
    }
    __syncthreads();
    float* ob = out + b * 65536;
    for (int p = 0; p < 4; p++) {
        int idx = p * 256 + tid;
        int r = idx >> 5, c = idx & 31;
        float v1 = 0.5f * (Ta[r * 33 + c] + Tb[c * 33 + r]);
        ob[(i0 + r) * 256 + j0 + c] = 1.f / (1.f + expf(-v1));
        float v2 = 0.5f * (Tb[r * 33 + c] + Ta[c * 33 + r]);
        ob[(j0 + r) * 256 + i0 + c] = 1.f / (1.f + expf(-v2));
    }
}

// ================= cooperative mega-kernel =================
struct P {
    const float *x, *adj, *W1, *b1, *W2, *b2, *W3, *b3, *g1, *be1, *g2, *be2;
    const float *e1w, *e1b, *e2w, *e2b, *e3w, *e3b;
    const float *f1w, *f1b, *f2w, *f2b, *f3w, *f3b;
    float* out;
    float *st1, *st2, *dg;
    unsigned short* bfr_g;
    float *An, *buf, *hb, *lg, *h1, *h2, *hi, *hj;
    unsigned* bars;
};

__global__ __launch_bounds__(256, 2) void k_fused(P p) {
    __shared__ float smem[12352];
    int bid = blockIdx.x, tid = threadIdx.x;
    unsigned* bars = p.bars;

    // S0: prologue (769 units)
    for (int u = bid; u < 769; u += 512) {
        pre_unit(u, tid, p.x, p.W1, p.adj, p.e2w, p.buf, p.dg, p.bfr_g, p.st1, smem);
        __syncthreads();
    }
    gbar(bars, 1);
    // S1 (L2): h1 = norm(adj)@buf + b1 (+stats->st1); An materialized
    if (bid < 256)
        dev_tile<256>(bid, p.adj, p.buf, p.b1, p.dg, p.An, 0, 0, 0, p.st1, p.h1,
                      128, 0, 65536, 32768, 32768, 4, 16, smem);
    gbar(bars, 2);
    // S2 (L3): buf = BN(h1)@W2
    if (bid < 256)
        dev_tile<128>(bid, p.h1, p.W2, 0, 0, 0, p.st1, p.g1, p.be1, 0, p.buf,
                      128, 0, 0, 0, 0, 4, 64, smem);
    gbar(bars, 3);
    // S3 (L4): h2 = An@buf + b2 (+stats->st2)
    if (bid < 256)
        dev_tile<256>(bid, p.An, p.buf, p.b2, 0, 0, 0, 0, 0, p.st2, p.h2,
                      128, 0, 65536, 32768, 32768, 4, 16, smem);
    gbar(bars, 4);
    // S4 (L5): buf = BN(h2)@W3   (512 units)
    dev_tile<128>(bid, p.h2, p.W3, 0, 0, 0, p.st2, p.g2, p.be2, 0, p.buf,
                  256, 0, 0, 0, 0, 8, 64, smem);
    gbar(bars, 5);
    // S5 (L6): hb = relu(An@buf + b3)   (512 units)
    dev_tile<256>(bid, p.An, p.buf, p.b3, 0, 0, 0, 0, 0, 0, p.hb,
                  256, 1, 65536, 65536, 65536, 8, 16, smem);
    gbar(bars, 6);
    // S6 (L7): hi/hj (batch-2) + f1 (768 units)
    for (int u = bid; u < 768; u += 512) {
        if (u < 512)
            dev_tile<256>(u, p.hb, p.e1w, 0, 0, 0, 0, 0, 0, 0, p.hi,
                          128, 0, 0, 32768, 131072, 4, 64, smem);
        else
            dev_tile<256>(u - 512, p.hb, p.f1w, p.f1b, 0, 0, 0, 0, 0, 0, p.h1,
                          128, 1, 0, 0, 0, 4, 64, smem);
        __syncthreads();
    }
    gbar(bars, 7);
    // S7 (L8): decoder + feature f2/f3 (1280 units)
    for (int u = bid; u < 1280; u += 512) {
        dec_unit(u, p.hi, p.hj, p.e1b, p.bfr_g, p.e2b, p.e3w, p.e3b,
                 p.h1, p.f2w, p.f2b, p.f3w, p.f3b, p.lg, p.out, smem);
        __syncthreads();
    }
    gbar(bars, 8);
    // S8 (L9): symmetrize + sigmoid (144 units)
    if (bid < 144)
        symsig_unit(bid, p.lg, p.out, smem);
}

// ================= fallback standalone kernels =================
__global__ void k_pre(const float* x, const float* W1, const float* adj,
                      const float* e2w, float* buf, float* dg,
                      unsigned short* bfr_g, float* st) {
    __shared__ float ss[256];
    pre_unit(blockIdx.x, threadIdx.x, x, W1, adj, e2w, buf, dg, bfr_g, st, ss);
}

template <int K>
__global__ __launch_bounds__(256, 3) void k_tgemm(
        const float* A, const float* B, const float* bias,
        const float* dgA, float* anOut,
        const float* stat, const float* g, const float* beta,
        float* ostat, float* C,
        int N, int relu,
        int sA, int sB, int sC, int tiles_n, int tiles_m) {
    __shared__ float smem[12352];
    dev_tile<K>(blockIdx.x, A, B, bias, dgA, anOut, stat, g, beta, ostat, C,
                N, relu, sA, sB, sC, tiles_n, tiles_m, smem);
}

__global__ __launch_bounds__(256, 3) void k_g67(
        const float* hb, const float* e1w, float* hi,
        const float* f1w, const float* f1b, float* f1) {
    __shared__ float smem[12352];
    int t = blockIdx.x;
    if (t < 512) {
        dev_tile<256>(t, hb, e1w, 0, 0, 0, 0, 0, 0, 0, hi,
                      128, 0, 0, 32768, 131072, 4, 64, smem);
    } else {
        dev_tile<256>(t - 512, hb, f1w, f1b, 0, 0, 0, 0, 0, 0, f1,
                      128, 1, 0, 0, 0, 4, 64, smem);
    }
}

__global__ void k_decf(const float* hi, const float* hj, const float* e1b,
                       const unsigned short* bfr_g, const float* e2b,
                       const float* e3w, const float* e3b,
                       const float* f1, const float* f2w, const float* f2b_,
                       const float* f3w, const float* f3b,
                       float* lg, float* out) {
    __shared__ float smem[4608];
    dec_unit(blockIdx.x, hi, hj, e1b, bfr_g, e2b, e3w, e3b,
             f1, f2w, f2b_, f3w, f3b, lg, out, smem);
}

__global__ void k_symsig(const float* lg, float* out) {
    __shared__ float smem[2 * 32 * 33];
    symsig_unit(blockIdx.x, lg, out, smem);
}

extern "C" void kernel_launch(void* const* d_in, const int* in_sizes, int n_in,
                              void* d_out, int out_size, void* d_ws, size_t ws_size,
                              hipStream_t stream) {
    const float* x   = (const float*)d_in[0];
    const float* adj = (const float*)d_in[1];
    const float* W1  = (const float*)d_in[2];
    const float* b1  = (const float*)d_in[3];
    const float* W2  = (const float*)d_in[4];
    const float* b2  = (const float*)d_in[5];
    const float* W3  = (const float*)d_in[6];
    const float* b3  = (const float*)d_in[7];
    const float* g1  = (const float*)d_in[8];
    const float* be1 = (const float*)d_in[9];
    const float* g2  = (const float*)d_in[10];
    const float* be2 = (const float*)d_in[11];
    const float* e1w = (const float*)d_in[12];
    const float* e1b = (const float*)d_in[13];
    const float* e2w = (const float*)d_in[14];
    const float* e2b = (const float*)d_in[15];
    const float* e3w = (const float*)d_in[16];
    const float* e3b = (const float*)d_in[17];
    const float* f1w = (const float*)d_in[18];
    const float* f1b = (const float*)d_in[19];
    const float* f2w = (const float*)d_in[20];
    const float* f2b_ = (const float*)d_in[21];
    const float* f3w = (const float*)d_in[22];
    const float* f3b = (const float*)d_in[23];

    float* out = (float*)d_out;

    if (ws_size < (size_t)1600000 * 4) {
        hipMemsetAsync(d_out, 0x60, 4096, stream);   // diagnostic
        return;
    }
    float* ws = (float*)d_ws;
    float* st1 = ws;                        // 256 (zeroed in pre)
    float* st2 = ws + 256;                  // 256 (zeroed in pre)
    float* dg  = ws + 512;                  // 1024
    unsigned short* bfr_g = (unsigned short*)(ws + 1536);   // 8192 us
    float* An  = ws + 5632;                 // 262144 (materialized by S1)
    float* buf = An + 262144;
    float* hb  = buf + 262144;
    float* lg  = hb + 262144;
    float* h1  = lg + 262144;               // 131072 (later reused as f1)
    float* h2  = h1 + 131072;
    float* hi  = h2 + 131072;
    float* hj  = hi + 131072;               // contiguous after hi (batch-2)
    unsigned* bars = (unsigned*)(hj + 131072);   // 320 uints (1280 B)

    P prm;
    prm.x = x; prm.adj = adj; prm.W1 = W1; prm.b1 = b1; prm.W2 = W2; prm.b2 = b2;
    prm.W3 = W3; prm.b3 = b3; prm.g1 = g1; prm.be1 = be1; prm.g2 = g2; prm.be2 = be2;
    prm.e1w = e1w; prm.e1b = e1b; prm.e2w = e2w; prm.e2b = e2b; prm.e3w = e3w; prm.e3b = e3b;
    prm.f1w = f1w; prm.f1b = f1b; prm.f2w = f2w; prm.f2b = f2b_; prm.f3w = f3w; prm.f3b = f3b;
    prm.out = out;
    prm.st1 = st1; prm.st2 = st2; prm.dg = dg; prm.bfr_g = bfr_g;
    prm.An = An; prm.buf = buf; prm.hb = hb; prm.lg = lg;
    prm.h1 = h1; prm.h2 = h2; prm.hi = hi; prm.hj = hj;
    prm.bars = bars;

    hipMemsetAsync(bars, 0, 1280, stream);   // zero barrier counters (in-graph)

    void* args[] = { (void*)&prm };
    hipError_t err = hipLaunchCooperativeKernel((const void*)k_fused,
                                                dim3(512), dim3(256),
                                                args, 0, stream);
    if (err == hipSuccess) return;
    (void)hipGetLastError();   // clear sticky error, fall back

    // ---- fallback: verified 9-launch schedule ----
    k_pre<<<769, 256, 0, stream>>>(x, W1, adj, e2w, buf, dg, bfr_g, st1);
    k_tgemm<256><<<256, 256, 0, stream>>>(adj, buf, b1, dg, An, 0, 0, 0, st1, h1,
                                          128, 0, 65536, 32768, 32768, 4, 16);
    k_tgemm<128><<<256, 256, 0, stream>>>(h1, W2, 0, 0, 0, st1, g1, be1, 0, buf,
                                          128, 0, 0, 0, 0, 4, 64);
    k_tgemm<256><<<256, 256, 0, stream>>>(An, buf, b2, 0, 0, 0, 0, 0, st2, h2,
                                          128, 0, 65536, 32768, 32768, 4, 16);
    k_tgemm<128><<<512, 256, 0, stream>>>(h2, W3, 0, 0, 0, st2, g2, be2, 0, buf,
                                          256, 0, 0, 0, 0, 8, 64);
    k_tgemm<256><<<512, 256, 0, stream>>>(An, buf, b3, 0, 0, 0, 0, 0, 0, hb,
                                          256, 1, 65536, 65536, 65536, 8, 16);
    k_g67<<<768, 256, 0, stream>>>(hb, e1w, hi, f1w, f1b, h1);
    k_decf<<<1280, 256, 0, stream>>>(hi, hj, e1b, bfr_g, e2b, e3w, e3b,
                                     h1, f2w, f2b_, f3w, f3b, lg, out);
    k_symsig<<<144, 256, 0, stream>>>(lg, out);
}

// Round 5
// 253.488 us; speedup vs baseline: 2.5585x; 1.4883x over previous
//
#include <hip/hip_runtime.h>

// Shapes (fixed): B=4, N=256, F=6, H=128, D=256, B*N=1024
// All tensors fp32. out = concat(adj_pred [4,256,256], feat_pred [4,256,6]).
// R5 = R4 resubmit (R4 bench died at container level, no kernel data).
// 6 launches. k_mid merges L3+L4 and L5+L6+L7 via associativity:
//   h2 = (An @ relu(BN(h1))) @ W2 + b2   [one block owns 16 full rows]
//   hb = (An @ relu(BN(h2))) @ W3 + b3 ; then row-local hi/hj/f1 inline.
// All other kernels verbatim from the verified 187us version.

typedef float v4f __attribute__((ext_vector_type(4)));
typedef short v8s __attribute__((ext_vector_type(8)));

__device__ __forceinline__ unsigned short f2bs(float f) {
    union { float f; unsigned int u; } v;
    v.f = f;
    return (unsigned short)((v.u + 0x7fffu + ((v.u >> 16) & 1u)) >> 16);
}

// ---- L0: role-split prologue (unchanged) ----
__global__ void k_pre(const float* x, const float* W1, const float* adj,
                      const float* e2w, float* buf, float* dg,
                      unsigned short* bfr_g, float* st) {
    __shared__ float ss[256];
    int blk = blockIdx.x, tid = threadIdx.x;
    if (blk < 512) {
        int idx = blk * 256 + tid;
        int m = idx >> 7, n = idx & 127;
        float s = 0.f;
        for (int k = 0; k < 6; k++) s += x[m * 6 + k] * W1[k * 128 + n];
        buf[idx] = s;
    } else if (blk < 768) {
        int row = (blk - 512) * 4 + (tid >> 6);
        int lane = tid & 63;
        const float* ap = adj + (long)row * 256;
        ss[tid] = ap[lane] + ap[lane + 64] + ap[lane + 128] + ap[lane + 192];
        __syncthreads();
        for (int o = 32; o > 0; o >>= 1) {
            if (lane < o) ss[tid] += ss[tid + o];
            __syncthreads();
        }
        if (lane == 0) {
            float t = ss[tid] + 1.f;
            if (t < 1.f) t = 1.f;
            dg[row] = rsqrtf(t);
        }
    } else {
        for (int s = tid; s < 8192; s += 256) {
            int k = s >> 6, n = s & 63;
            int kc = k >> 5, q = (k & 31) >> 3, t = k & 7;
            int nt = n >> 4, c2 = n & 15;
            bfr_g[(((nt * 4 + kc) * 64) + q * 16 + c2) * 8 + t] = f2bs(e2w[s]);
        }
        st[tid] = 0.f;
        st[256 + tid] = 0.f;
    }
}

// ---- tiled GEMM (unchanged, used for L2 only) ----
template <int K>
__device__ __forceinline__ void dev_tile(
        int t, const float* A, const float* B, const float* bias,
        const float* dgA, float* anOut,
        const float* stat, const float* g, const float* beta,
        float* ostat, float* C,
        int N, int relu,
        int sA, int sB, int sC, int tiles_n, int tiles_m,
        float* smem) {
    constexpr int strideA = K + 4;
    constexpr int NCH = K / 16;
    float* As = smem;
    float* Bs = smem + 4160;
    int tid = threadIdx.x;
    int n2 = tid & 15, ml = tid >> 4;
    int bx = t % tiles_n;
    int tmp = t / tiles_n;
    int by = tmp % tiles_m;
    int bz = tmp / tiles_m;
    int m0 = by * 16, n0 = bx * 32;
    const float* Ab = A + (long)bz * sA;
    const float* Bb = B + (long)bz * sB;
    float* Cb = C + (long)bz * sC;
    const float* dgb = (dgA != 0) ? (dgA + bz * 256) : 0;

    int kk = tid & 15, mm = tid >> 4;
    int nb = tid & 31, kb = tid >> 5;

    float b0_r[NCH], b1_r[NCH], a_r[NCH];
    const float* Arow = Ab + (long)(m0 + mm) * K;
    #pragma unroll
    for (int i = 0; i < NCH; i++) {
        a_r[i]  = Arow[i * 16 + kk];
        b0_r[i] = Bb[(long)(i * 16 + kb) * N + n0 + nb];
        b1_r[i] = Bb[(long)(i * 16 + kb + 8) * N + n0 + nb];
    }

    if (dgA != 0) {
        float di = dgb[m0 + mm];
        float d_r[NCH];
        #pragma unroll
        for (int i = 0; i < NCH; i++) d_r[i] = dgb[i * 16 + kk];
        #pragma unroll
        for (int i = 0; i < NCH; i++) {
            int kg = i * 16 + kk;
            float v = a_r[i];
            if (m0 + mm == kg) v += 1.f;
            v = di * v * d_r[i];
            if (anOut != 0 && bx == 0)
                anOut[bz * 65536 + (m0 + mm) * 256 + kg] = v;
            As[mm * strideA + kg] = v;
        }
    } else if (stat != 0) {
        float s_r[NCH], q_r[NCH], g_r[NCH], be_r[NCH];
        #pragma unroll
        for (int i = 0; i < NCH; i++) {
            int kg = i * 16 + kk;
            s_r[i]  = stat[kg];
            q_r[i]  = stat[128 + kg];
            g_r[i]  = g[kg];
            be_r[i] = beta[kg];
        }
        #pragma unroll
        for (int i = 0; i < NCH; i++) {
            int kg = i * 16 + kk;
            float mu = s_r[i] * (1.f / 1024.f);
            float vr = q_r[i] * (1.f / 1024.f) - mu * mu;
            float sc = rsqrtf(vr + 1e-5f) * g_r[i];
            float v = (a_r[i] - mu) * sc + be_r[i];
            if (v < 0.f) v = 0.f;
            As[mm * strideA + kg] = v;
        }
    } else {
        #pragma unroll
        for (int i = 0; i < NCH; i++)
            As[mm * strideA + i * 16 + kk] = a_r[i];
    }
    #pragma unroll
    for (int i = 0; i < NCH; i++) {
        Bs[(i * 16 + kb) * 32 + nb] = b0_r[i];
        Bs[(i * 16 + kb + 8) * 32 + nb] = b1_r[i];
    }
    __syncthreads();

    float c0a = 0.f, c0b = 0.f, c1a = 0.f, c1b = 0.f;
    const float* arow = As + ml * strideA;
    const float* bcol = Bs + n2 * 2;
    #pragma unroll
    for (int q0 = 0; q0 < K; q0 += 4) {
        float4 av = *(const float4*)(arow + q0);
        float2 b0 = *(const float2*)(bcol + (q0 + 0) * 32);
        float2 b1 = *(const float2*)(bcol + (q0 + 1) * 32);
        float2 b2 = *(const float2*)(bcol + (q0 + 2) * 32);
        float2 b3 = *(const float2*)(bcol + (q0 + 3) * 32);
        c0a += av.x * b0.x; c1a += av.x * b0.y;
        c0b += av.y * b1.x; c1b += av.y * b1.y;
        c0a += av.z * b2.x; c1a += av.z * b2.y;
        c0b += av.w * b3.x; c1b += av.w * b3.y;
    }
    float c0 = c0a + c0b, c1 = c1a + c1b;
    int mRow = m0 + ml, nn = n0 + n2 * 2;
    if (bias != 0) { c0 += bias[nn]; c1 += bias[nn + 1]; }
    if (relu) {
        if (c0 < 0.f) c0 = 0.f;
        if (c1 < 0.f) c1 = 0.f;
    }
    Cb[(long)mRow * N + nn] = c0;
    Cb[(long)mRow * N + nn + 1] = c1;

    if (ostat != 0) {
        float* sred = smem;
        float* qred = smem + 544;
        __syncthreads();
        sred[(n2 * 2) * 17 + ml] = c0;
        sred[(n2 * 2 + 1) * 17 + ml] = c1;
        qred[(n2 * 2) * 17 + ml] = c0 * c0;
        qred[(n2 * 2 + 1) * 17 + ml] = c1 * c1;
        __syncthreads();
        if (tid < 32) {
            float s = 0.f, q = 0.f;
            for (int u = 0; u < 16; u++) {
                s += sred[tid * 17 + u];
                q += qred[tid * 17 + u];
            }
            atomicAdd(&ostat[n0 + tid], s);
            atomicAdd(&ostat[128 + n0 + tid], q);
        }
    }
}

template <int K>
__global__ __launch_bounds__(256, 3) void k_tgemm(
        const float* A, const float* B, const float* bias,
        const float* dgA, float* anOut,
        const float* stat, const float* g, const float* beta,
        float* ostat, float* C,
        int N, int relu,
        int sA, int sB, int sC, int tiles_n, int tiles_m) {
    __shared__ float smem[12352];
    dev_tile<K>(blockIdx.x, A, B, bias, dgA, anOut, stat, g, beta, ostat, C,
                N, relu, sA, sB, sC, tiles_n, tiles_m, smem);
}

// ---- k_mid: OUT_rows = (An_rows @ relu(BN(Hin))) @ W + bias ----
// grid 64 = (bz 0..3) x (mt 0..15); 512 threads; block owns 16 full rows.
// NW: W cols (128 or 256). STATS: column sum/sq atomics into ostat.
// RELU: relu on OUT. G67: inline hi/hj/f1 projections from hb rows.
template <int NW, int STATS, int RELU, int G67>
__global__ __launch_bounds__(512, 1) void k_mid(
        const float* __restrict__ An, const float* __restrict__ Hin,
        const float* __restrict__ W, const float* __restrict__ bias,
        const float* __restrict__ st, const float* __restrict__ g,
        const float* __restrict__ beta, float* ostat, float* OUT,
        const float* __restrict__ e1w, const float* __restrict__ f1w,
        const float* __restrict__ f1b,
        float* hi, float* hj, float* f1) {
    __shared__ float sm[10752];
    float* sl  = sm;            // [128] BN scale
    float* sh  = sm + 128;      // [128] BN shift
    float* An_s = sm + 256;     // [16][260]
    float* P_s  = sm + 4416;    // [32][132]
    float* T_s  = sm + 8640;    // [16][132]

    int t = threadIdx.x;
    int bz = blockIdx.x >> 4, mt = blockIdx.x & 15;
    int m0 = mt * 16;
    int r = t >> 5, cg = t & 31;

    // step 0: BN scale/shift + An row staging
    if (t < 128) {
        float mu = st[t] * (1.f / 1024.f);
        float vr = st[128 + t] * (1.f / 1024.f) - mu * mu;
        float sc = rsqrtf(vr + 1e-5f) * g[t];
        sl[t] = sc;
        sh[t] = beta[t] - mu * sc;
    }
    {
        const float* Ag = An + (long)bz * 65536 + (long)m0 * 256 + t * 8;
        float4 a0 = *(const float4*)Ag;
        float4 a1 = *(const float4*)(Ag + 4);
        float* d = An_s + r * 260 + cg * 8;
        d[0] = a0.x; d[1] = a0.y; d[2] = a0.z; d[3] = a0.w;
        d[4] = a1.x; d[5] = a1.y; d[6] = a1.z; d[7] = a1.w;
    }

    // step A: T = An_rows @ relu(BN(Hin)), k-panels of 32
    float4 acc = {0.f, 0.f, 0.f, 0.f};
    for (int p = 0; p < 8; ++p) {
        __syncthreads();
        {
            int kl = t >> 4, c = (t & 15) * 8;
            const float* src = Hin + (long)bz * 32768 + (p * 32 + kl) * 128 + c;
            float4 v0 = *(const float4*)src;
            float4 v1 = *(const float4*)(src + 4);
            float* d = P_s + kl * 132 + c;
            float o;
            o = v0.x * sl[c + 0] + sh[c + 0]; d[0] = o > 0.f ? o : 0.f;
            o = v0.y * sl[c + 1] + sh[c + 1]; d[1] = o > 0.f ? o : 0.f;
            o = v0.z * sl[c + 2] + sh[c + 2]; d[2] = o > 0.f ? o : 0.f;
            o = v0.w * sl[c + 3] + sh[c + 3]; d[3] = o > 0.f ? o : 0.f;
            o = v1.x * sl[c + 4] + sh[c + 4]; d[4] = o > 0.f ? o : 0.f;
            o = v1.y * sl[c + 5] + sh[c + 5]; d[5] = o > 0.f ? o : 0.f;
            o = v1.z * sl[c + 6] + sh[c + 6]; d[6] = o > 0.f ? o : 0.f;
            o = v1.w * sl[c + 7] + sh[c + 7]; d[7] = o > 0.f ? o : 0.f;
        }
        __syncthreads();
        const float* ar = An_s + r * 260 + p * 32;
        #pragma unroll
        for (int kk = 0; kk < 32; ++kk) {
            float a = ar[kk];
            float4 pv = *(const float4*)(P_s + kk * 132 + cg * 4);
            acc.x += a * pv.x; acc.y += a * pv.y;
            acc.z += a * pv.z; acc.w += a * pv.w;
        }
    }
    {
        float* d = T_s + r * 132 + cg * 4;
        d[0] = acc.x; d[1] = acc.y; d[2] = acc.z; d[3] = acc.w;
    }
    __syncthreads();

    // step B: OUT rows = T @ W + bias
    float4 o0 = *(const float4*)(bias + cg * 4);
    float4 o1 = {0.f, 0.f, 0.f, 0.f};
    if (NW == 256) o1 = *(const float4*)(bias + 128 + cg * 4);
    const float* tr = T_s + r * 132;
    #pragma unroll 4
    for (int c = 0; c < 128; ++c) {
        float tv = tr[c];
        const float4 w0 = *(const float4*)(W + (long)c * NW + cg * 4);
        o0.x += tv * w0.x; o0.y += tv * w0.y;
        o0.z += tv * w0.z; o0.w += tv * w0.w;
        if (NW == 256) {
            const float4 w1 = *(const float4*)(W + (long)c * NW + 128 + cg * 4);
            o1.x += tv * w1.x; o1.y += tv * w1.y;
            o1.z += tv * w1.z; o1.w += tv * w1.w;
        }
    }

    if (STATS) {
        float* red_s = An_s;   // 128*17 = 2176 <= 4160
        float* red_q = P_s;    // 2176 <= 4224
        red_s[(cg * 4 + 0) * 17 + r] = o0.x;
        red_s[(cg * 4 + 1) * 17 + r] = o0.y;
        red_s[(cg * 4 + 2) * 17 + r] = o0.z;
        red_s[(cg * 4 + 3) * 17 + r] = o0.w;
        red_q[(cg * 4 + 0) * 17 + r] = o0.x * o0.x;
        red_q[(cg * 4 + 1) * 17 + r] = o0.y * o0.y;
        red_q[(cg * 4 + 2) * 17 + r] = o0.z * o0.z;
        red_q[(cg * 4 + 3) * 17 + r] = o0.w * o0.w;
        __syncthreads();
        if (t < 128) {
            float s = 0.f, q = 0.f;
            #pragma unroll
            for (int u = 0; u < 16; ++u) {
                s += red_s[t * 17 + u];
                q += red_q[t * 17 + u];
            }
            atomicAdd(&ostat[t], s);
            atomicAdd(&ostat[128 + t], q);
        }
    }

    if (RELU) {
        if (o0.x < 0.f) o0.x = 0.f;
        if (o0.y < 0.f) o0.y = 0.f;
        if (o0.z < 0.f) o0.z = 0.f;
        if (o0.w < 0.f) o0.w = 0.f;
        if (NW == 256) {
            if (o1.x < 0.f) o1.x = 0.f;
            if (o1.y < 0.f) o1.y = 0.f;
            if (o1.z < 0.f) o1.z = 0.f;
            if (o1.w < 0.f) o1.w = 0.f;
        }
    }

    if (OUT != 0) {
        if (NW == 128) {
            float* d = OUT + (long)bz * 32768 + (long)(m0 + r) * 128 + cg * 4;
            *(float4*)d = o0;
        } else {
            float* d = OUT + (long)bz * 65536 + (long)(m0 + r) * 256 + cg * 4;
            *(float4*)d = o0;
            *(float4*)(d + 128) = o1;
        }
    }

    // step C: row-local projections hi/hj/f1 from hb rows (G67 only)
    if (G67) {
        float* hb_s = An_s;   // reuse [16][260]; An_s reads finished in step A
        float* d = hb_s + r * 260 + cg * 4;
        d[0] = o0.x; d[1] = o0.y; d[2] = o0.z; d[3] = o0.w;
        d[128] = o1.x; d[129] = o1.y; d[130] = o1.z; d[131] = o1.w;
        __syncthreads();
        const float* hr = hb_s + r * 260;
        #pragma unroll 1
        for (int pass = 0; pass < 3; ++pass) {
            const float* Wc = (pass == 0) ? e1w
                            : (pass == 1) ? (e1w + 32768) : f1w;
            float4 a = {0.f, 0.f, 0.f, 0.f};
            if (pass == 2) a = *(const float4*)(f1b + cg * 4);
            #pragma unroll 4
            for (int c = 0; c < 256; ++c) {
                float hv = hr[c];
                const float4 w4 = *(const float4*)(Wc + (long)c * 128 + cg * 4);
                a.x += hv * w4.x; a.y += hv * w4.y;
                a.z += hv * w4.z; a.w += hv * w4.w;
            }
            if (pass == 2) {
                if (a.x < 0.f) a.x = 0.f;
                if (a.y < 0.f) a.y = 0.f;
                if (a.z < 0.f) a.z = 0.f;
                if (a.w < 0.f) a.w = 0.f;
            }
            float* dst = ((pass == 0) ? hi : (pass == 1) ? hj : f1)
                         + ((long)bz * 256 + m0 + r) * 128 + cg * 4;
            *(float4*)dst = a;
        }
    }
}

// ---- L8: {MFMA pair decoder} + {feature f2/f3} (unchanged) ----
__global__ void k_decf(const float* hi, const float* hj, const float* e1b,
                       const unsigned short* bfr_g, const float* e2b,
                       const float* e3w, const float* e3b,
                       const float* f1, const float* f2w, const float* f2b_,
                       const float* f3w, const float* f3b,
                       float* lg, float* out) {
    __shared__ float smem[4608];
    int tid = threadIdx.x;
    int blk = blockIdx.x;
    if (blk < 1024) {
        float* red = smem;
        float* pre_sh = smem + 4352;
        int lane = tid & 63, wv = tid >> 6;
        int col = lane & 15, quad = lane >> 4;
        int bi = blk, b = bi >> 8;
        if (tid < 128) pre_sh[tid] = hi[bi * 128 + tid] + e1b[tid];
        __syncthreads();
        float e2bv[4], e3wv[4];
        for (int nt = 0; nt < 4; nt++) {
            e2bv[nt] = e2b[nt * 16 + col];
            e3wv[nt] = e3w[nt * 16 + col];
        }
        const float* hjb = hj + b * 32768;
        #pragma unroll 1
        for (int ms = 0; ms < 4; ms++) {
            v4f acc[4];
            for (int nt = 0; nt < 4; nt++) {
                v4f z = {0.f, 0.f, 0.f, 0.f};
                acc[nt] = z;
            }
            int j = wv * 64 + ms * 16 + col;
            const float* rowp = hjb + j * 128 + quad * 8;
            #pragma unroll 1
            for (int kc = 0; kc < 4; kc++) {
                const float* pp = pre_sh + kc * 32 + quad * 8;
                const float* hp = rowp + kc * 32;
                v8s af;
                #pragma unroll
                for (int t = 0; t < 8; t++) {
                    float p = pp[t] + hp[t];
                    p = (p > 0.f) ? p : 0.f;
                    af[t] = (short)f2bs(p);
                }
                #pragma unroll
                for (int nt = 0; nt < 4; nt++) {
                    v8s bf = *(const v8s*)&bfr_g[(((nt * 4 + kc) * 64) + lane) * 8];
                    acc[nt] = __builtin_amdgcn_mfma_f32_16x16x32_bf16(
                        af, bf, acc[nt], 0, 0, 0);
                }
            }
            #pragma unroll
            for (int r = 0; r < 4; r++) {
                float s = 0.f;
                #pragma unroll
                for (int nt = 0; nt < 4; nt++) {
                    float v = acc[nt][r] + e2bv[nt];
                    if (v > 0.f) s += v * e3wv[nt];
                }
                red[(wv * 64 + ms * 16 + quad * 4 + r) * 17 + col] = s;
            }
        }
        __syncthreads();
        float s = e3b[0];
        for (int c = 0; c < 16; c++) s += red[tid * 17 + c];
        lg[bi * 256 + tid] = s;
    } else {
        float* f2row = smem;
        int r0 = (blk - 1024) * 4;
        for (int p = 0; p < 2; p++) {
            int idx = tid + p * 256;
            int r = r0 + (idx >> 7), n = idx & 127;
            const float* f1r = f1 + (long)r * 128;
            float s0 = 0.f, s1 = 0.f, s2 = 0.f, s3 = 0.f;
            #pragma unroll
            for (int k = 0; k < 128; k += 4) {
                float4 fv = *(const float4*)(f1r + k);
                s0 += fv.x * f2w[(k + 0) * 128 + n];
                s1 += fv.y * f2w[(k + 1) * 128 + n];
                s2 += fv.z * f2w[(k + 2) * 128 + n];
                s3 += fv.w * f2w[(k + 3) * 128 + n];
            }
            float s = f2b_[n] + ((s0 + s1) + (s2 + s3));
            if (s < 0.f) s = 0.f;
            f2row[idx] = s;
        }
        __syncthreads();
        if (tid < 24) {
            int r = tid / 6, c = tid % 6;
            float s = f3b[c];
            const float* fr = f2row + r * 128;
            for (int k = 0; k < 128; k++) s += fr[k] * f3w[k * 6 + c];
            out[262144 + (r0 + r) * 6 + c] = s;
        }
    }
}

// ---- L9: tiled symmetrize + sigmoid (unchanged) ----
__global__ void k_symsig(const float* lg, float* out) {
    __shared__ float Ta[32 * 33];
    __shared__ float Tb[32 * 33];
    int tid = threadIdx.x;
    int b = blockIdx.x / 36;
    int t = blockIdx.x % 36;
    int ti = 0, rem = t;
    while (rem >= 8 - ti) { rem -= 8 - ti; ti++; }
    int tj = ti + rem;
    int i0 = ti * 32, j0 = tj * 32;
    const float* lgb = lg + b * 65536;
    for (int p = 0; p < 4; p++) {
        int idx = p * 256 + tid;
        int r = idx >> 5, c = idx & 31;
        Ta[r * 33 + c] = lgb[(i0 + r) * 256 + j0 + c];
        Tb[r * 33 + c] = lgb[(j0 + r) * 256 + i0 + c];
    }
    __syncthreads();
    float* ob = out + b * 65536;
    for (int p = 0; p < 4; p++) {
        int idx = p * 256 + tid;
        int r = idx >> 5, c = idx & 31;
        float v1 = 0.5f * (Ta[r * 33 + c] + Tb[c * 33 + r]);
        ob[(i0 + r) * 256 + j0 + c] = 1.f / (1.f + expf(-v1));
        float v2 = 0.5f * (Tb[r * 33 + c] + Ta[c * 33 + r]);
        ob[(j0 + r) * 256 + i0 + c] = 1.f / (1.f + expf(-v2));
    }
}

extern "C" void kernel_launch(void* const* d_in, const int* in_sizes, int n_in,
                              void* d_out, int out_size, void* d_ws, size_t ws_size,
                              hipStream_t stream) {
    const float* x   = (const float*)d_in[0];
    const float* adj = (const float*)d_in[1];
    const float* W1  = (const float*)d_in[2];
    const float* b1  = (const float*)d_in[3];
    const float* W2  = (const float*)d_in[4];
    const float* b2  = (const float*)d_in[5];
    const float* W3  = (const float*)d_in[6];
    const float* b3  = (const float*)d_in[7];
    const float* g1  = (const float*)d_in[8];
    const float* be1 = (const float*)d_in[9];
    const float* g2  = (const float*)d_in[10];
    const float* be2 = (const float*)d_in[11];
    const float* e1w = (const float*)d_in[12];
    const float* e1b = (const float*)d_in[13];
    const float* e2w = (const float*)d_in[14];
    const float* e2b = (const float*)d_in[15];
    const float* e3w = (const float*)d_in[16];
    const float* e3b = (const float*)d_in[17];
    const float* f1w = (const float*)d_in[18];
    const float* f1b = (const float*)d_in[19];
    const float* f2w = (const float*)d_in[20];
    const float* f2b_ = (const float*)d_in[21];
    const float* f3w = (const float*)d_in[22];
    const float* f3b = (const float*)d_in[23];

    float* out = (float*)d_out;

    if (ws_size < (size_t)1600000 * 4) {
        hipMemsetAsync(d_out, 0x60, 4096, stream);   // diagnostic
        return;
    }
    float* ws = (float*)d_ws;
    float* st1 = ws;                        // 256 (zeroed in k_pre)
    float* st2 = ws + 256;                  // 256 (zeroed in k_pre)
    float* dg  = ws + 512;                  // 1024
    unsigned short* bfr_g = (unsigned short*)(ws + 1536);   // 8192 us
    float* An  = ws + 5632;                 // 262144 (materialized by L2)
    float* buf = An + 262144;
    float* hb  = buf + 262144;              // unused now (hb kept in-registers)
    float* lg  = hb + 262144;
    float* h1  = lg + 262144;               // 131072 (later reused as f1)
    float* h2  = h1 + 131072;
    float* hi  = h2 + 131072;
    float* hj  = hi + 131072;               // contiguous after hi

    // L0: x@W1 + degree + e2w swizzle + zero BN accumulators
    k_pre<<<769, 256, 0, stream>>>(x, W1, adj, e2w, buf, dg, bfr_g, st1);
    // L2: h1 = norm(adj)@buf + b1 (+stats->st1); An materialized
    k_tgemm<256><<<256, 256, 0, stream>>>(adj, buf, b1, dg, An, 0, 0, 0, st1, h1,
                                          128, 0, 65536, 32768, 32768, 4, 16);
    // L34: h2 = (An @ relu(BN(h1;st1,g1,be1))) @ W2 + b2   (+stats -> st2)
    k_mid<128, 1, 0, 0><<<64, 512, 0, stream>>>(
        An, h1, W2, b2, st1, g1, be1, st2, h2, 0, 0, 0, 0, 0, 0);
    // L567: hb = relu((An @ relu(BN(h2;st2,g2,be2))) @ W3 + b3); hi/hj/f1 inline
    k_mid<256, 0, 1, 1><<<64, 512, 0, stream>>>(
        An, h2, W3, b3, st2, g2, be2, 0, 0, e1w, f1w, f1b, hi, hj, h1);
    // L8: decoder + feature f2/f3
    k_decf<<<1280, 256, 0, stream>>>(hi, hj, e1b, bfr_g, e2b, e3w, e3b,
                                     h1, f2w, f2b_, f3w, f3b, lg, out);
    // L9: tiled symmetrize + sigmoid
    k_symsig<<<144, 256, 0, stream>>>(lg, out);
}

// Round 6
// 183.454 us; speedup vs baseline: 3.5353x; 1.3818x over previous
//
#include <hip/hip_runtime.h>

// Shapes (fixed): B=4, N=256, F=6, H=128, D=256, B*N=1024
// All tensors fp32. out = concat(adj_pred [4,256,256], feat_pred [4,256,6]).
// R6: revert to verified 187us 9-launch schedule (R1). One change vs R1:
// k_decf decoder kc-loop un-serialized (hj row prefetched via 8x float4,
// kc fully unrolled) to break the global-load latency chain behind MFMA.

typedef float v4f __attribute__((ext_vector_type(4)));
typedef short v8s __attribute__((ext_vector_type(8)));

__device__ __forceinline__ unsigned short f2bs(float f) {
    union { float f; unsigned int u; } v;
    v.f = f;
    return (unsigned short)((v.u + 0x7fffu + ((v.u >> 16) & 1u)) >> 16);
}

// ---- L0: role-split prologue ----
__global__ void k_pre(const float* x, const float* W1, const float* adj,
                      const float* e2w, float* buf, float* dg,
                      unsigned short* bfr_g, float* st) {
    __shared__ float ss[256];
    int blk = blockIdx.x, tid = threadIdx.x;
    if (blk < 512) {
        int idx = blk * 256 + tid;
        int m = idx >> 7, n = idx & 127;
        float s = 0.f;
        for (int k = 0; k < 6; k++) s += x[m * 6 + k] * W1[k * 128 + n];
        buf[idx] = s;
    } else if (blk < 768) {
        int row = (blk - 512) * 4 + (tid >> 6);
        int lane = tid & 63;
        const float* ap = adj + (long)row * 256;
        ss[tid] = ap[lane] + ap[lane + 64] + ap[lane + 128] + ap[lane + 192];
        __syncthreads();
        for (int o = 32; o > 0; o >>= 1) {
            if (lane < o) ss[tid] += ss[tid + o];
            __syncthreads();
        }
        if (lane == 0) {
            float t = ss[tid] + 1.f;
            if (t < 1.f) t = 1.f;
            dg[row] = rsqrtf(t);
        }
    } else {
        for (int s = tid; s < 8192; s += 256) {
            int k = s >> 6, n = s & 63;
            int kc = k >> 5, q = (k & 31) >> 3, t = k & 7;
            int nt = n >> 4, c2 = n & 15;
            bfr_g[(((nt * 4 + kc) * 64) + q * 16 + c2) * 8 + t] = f2bs(e2w[s]);
        }
        st[tid] = 0.f;
        st[256 + tid] = 0.f;
    }
}

// ---- tiled GEMM, 16x32 tile, compile-time K, reg-staged loads ----
template <int K>
__device__ __forceinline__ void dev_tile(
        int t, const float* A, const float* B, const float* bias,
        const float* dgA, float* anOut,
        const float* stat, const float* g, const float* beta,
        float* ostat, float* C,
        int N, int relu,
        int sA, int sB, int sC, int tiles_n, int tiles_m,
        float* smem) {
    constexpr int strideA = K + 4;
    constexpr int NCH = K / 16;
    float* As = smem;                 // [16][K+4]  <= 4160
    float* Bs = smem + 4160;          // [K][32]    <= 8192
    int tid = threadIdx.x;
    int n2 = tid & 15, ml = tid >> 4;
    int bx = t % tiles_n;
    int tmp = t / tiles_n;
    int by = tmp % tiles_m;
    int bz = tmp / tiles_m;
    int m0 = by * 16, n0 = bx * 32;
    const float* Ab = A + (long)bz * sA;
    const float* Bb = B + (long)bz * sB;
    float* Cb = C + (long)bz * sC;
    const float* dgb = (dgA != 0) ? (dgA + bz * 256) : 0;

    int kk = tid & 15, mm = tid >> 4;
    int nb = tid & 31, kb = tid >> 5;

    // phase 1: issue ALL global loads into registers (one round trip)
    float b0_r[NCH], b1_r[NCH], a_r[NCH];
    const float* Arow = Ab + (long)(m0 + mm) * K;
    #pragma unroll
    for (int i = 0; i < NCH; i++) {
        a_r[i]  = Arow[i * 16 + kk];
        b0_r[i] = Bb[(long)(i * 16 + kb) * N + n0 + nb];
        b1_r[i] = Bb[(long)(i * 16 + kb + 8) * N + n0 + nb];
    }

    // phase 2: per-path A processing + LDS writes
    if (dgA != 0) {
        float di = dgb[m0 + mm];
        float d_r[NCH];
        #pragma unroll
        for (int i = 0; i < NCH; i++) d_r[i] = dgb[i * 16 + kk];
        #pragma unroll
        for (int i = 0; i < NCH; i++) {
            int kg = i * 16 + kk;
            float v = a_r[i];
            if (m0 + mm == kg) v += 1.f;
            v = di * v * d_r[i];
            if (anOut != 0 && bx == 0)
                anOut[bz * 65536 + (m0 + mm) * 256 + kg] = v;
            As[mm * strideA + kg] = v;
        }
    } else if (stat != 0) {
        float s_r[NCH], q_r[NCH], g_r[NCH], be_r[NCH];
        #pragma unroll
        for (int i = 0; i < NCH; i++) {
            int kg = i * 16 + kk;
            s_r[i]  = stat[kg];
            q_r[i]  = stat[128 + kg];
            g_r[i]  = g[kg];
            be_r[i] = beta[kg];
        }
        #pragma unroll
        for (int i = 0; i < NCH; i++) {
            int kg = i * 16 + kk;
            float mu = s_r[i] * (1.f / 1024.f);
            float vr = q_r[i] * (1.f / 1024.f) - mu * mu;
            float sc = rsqrtf(vr + 1e-5f) * g_r[i];
            float v = (a_r[i] - mu) * sc + be_r[i];
            if (v < 0.f) v = 0.f;
            As[mm * strideA + kg] = v;
        }
    } else {
        #pragma unroll
        for (int i = 0; i < NCH; i++)
            As[mm * strideA + i * 16 + kk] = a_r[i];
    }
    #pragma unroll
    for (int i = 0; i < NCH; i++) {
        Bs[(i * 16 + kb) * 32 + nb] = b0_r[i];
        Bs[(i * 16 + kb + 8) * 32 + nb] = b1_r[i];
    }
    __syncthreads();

    // inner product: fully unrolled, split accumulators
    float c0a = 0.f, c0b = 0.f, c1a = 0.f, c1b = 0.f;
    const float* arow = As + ml * strideA;
    const float* bcol = Bs + n2 * 2;
    #pragma unroll
    for (int q0 = 0; q0 < K; q0 += 4) {
        float4 av = *(const float4*)(arow + q0);
        float2 b0 = *(const float2*)(bcol + (q0 + 0) * 32);
        float2 b1 = *(const float2*)(bcol + (q0 + 1) * 32);
        float2 b2 = *(const float2*)(bcol + (q0 + 2) * 32);
        float2 b3 = *(const float2*)(bcol + (q0 + 3) * 32);
        c0a += av.x * b0.x; c1a += av.x * b0.y;
        c0b += av.y * b1.x; c1b += av.y * b1.y;
        c0a += av.z * b2.x; c1a += av.z * b2.y;
        c0b += av.w * b3.x; c1b += av.w * b3.y;
    }
    float c0 = c0a + c0b, c1 = c1a + c1b;
    int mRow = m0 + ml, nn = n0 + n2 * 2;
    if (bias != 0) { c0 += bias[nn]; c1 += bias[nn + 1]; }
    if (relu) {
        if (c0 < 0.f) c0 = 0.f;
        if (c1 < 0.f) c1 = 0.f;
    }
    Cb[(long)mRow * N + nn] = c0;
    Cb[(long)mRow * N + nn + 1] = c1;

    if (ostat != 0) {
        float* sred = smem;
        float* qred = smem + 544;
        __syncthreads();
        sred[(n2 * 2) * 17 + ml] = c0;
        sred[(n2 * 2 + 1) * 17 + ml] = c1;
        qred[(n2 * 2) * 17 + ml] = c0 * c0;
        qred[(n2 * 2 + 1) * 17 + ml] = c1 * c1;
        __syncthreads();
        if (tid < 32) {
            float s = 0.f, q = 0.f;
            for (int u = 0; u < 16; u++) {
                s += sred[tid * 17 + u];
                q += qred[tid * 17 + u];
            }
            atomicAdd(&ostat[n0 + tid], s);
            atomicAdd(&ostat[128 + n0 + tid], q);
        }
    }
}

template <int K>
__global__ __launch_bounds__(256, 3) void k_tgemm(
        const float* A, const float* B, const float* bias,
        const float* dgA, float* anOut,
        const float* stat, const float* g, const float* beta,
        float* ostat, float* C,
        int N, int relu,
        int sA, int sB, int sC, int tiles_n, int tiles_m) {
    __shared__ float smem[12352];
    dev_tile<K>(blockIdx.x, A, B, bias, dgA, anOut, stat, g, beta, ostat, C,
                N, relu, sA, sB, sC, tiles_n, tiles_m, smem);
}

// ---- L7: {hi|hj = hb@e1w (batch-2)} + {f1 = relu(hb@f1w+f1b)} ----
__global__ __launch_bounds__(256, 3) void k_g67(
        const float* hb, const float* e1w, float* hi,
        const float* f1w, const float* f1b, float* f1) {
    __shared__ float smem[12352];
    int t = blockIdx.x;
    if (t < 512) {
        dev_tile<256>(t, hb, e1w, 0, 0, 0, 0, 0, 0, 0, hi,
                      128, 0, 0, 32768, 131072, 4, 64, smem);
    } else {
        dev_tile<256>(t - 512, hb, f1w, f1b, 0, 0, 0, 0, 0, 0, f1,
                      128, 1, 0, 0, 0, 4, 64, smem);
    }
}

// ---- L8: {MFMA pair decoder} + {feature f2/f3} ----
// R6 change: hj row slice prefetched (8x float4, one round trip), kc loop
// fully unrolled -> global-load latency no longer serialized behind MFMA.
__global__ void k_decf(const float* hi, const float* hj, const float* e1b,
                       const unsigned short* bfr_g, const float* e2b,
                       const float* e3w, const float* e3b,
                       const float* f1, const float* f2w, const float* f2b_,
                       const float* f3w, const float* f3b,
                       float* lg, float* out) {
    __shared__ float smem[4608];
    int tid = threadIdx.x;
    int blk = blockIdx.x;
    if (blk < 1024) {
        float* red = smem;                           // [256][17] = 4352
        float* pre_sh = smem + 4352;                 // 128
        int lane = tid & 63, wv = tid >> 6;
        int col = lane & 15, quad = lane >> 4;
        int bi = blk, b = bi >> 8;
        if (tid < 128) pre_sh[tid] = hi[bi * 128 + tid] + e1b[tid];
        __syncthreads();
        float e2bv[4], e3wv[4];
        for (int nt = 0; nt < 4; nt++) {
            e2bv[nt] = e2b[nt * 16 + col];
            e3wv[nt] = e3w[nt * 16 + col];
        }
        const float* hjb = hj + b * 32768;
        #pragma unroll 1
        for (int ms = 0; ms < 4; ms++) {
            v4f acc[4];
            for (int nt = 0; nt < 4; nt++) {
                v4f z = {0.f, 0.f, 0.f, 0.f};
                acc[nt] = z;
            }
            int j = wv * 64 + ms * 16 + col;
            const float* rowp = hjb + j * 128 + quad * 8;
            // prefetch the full 32-float hj slice for this row (one RT)
            float hjr[32];
            #pragma unroll
            for (int q = 0; q < 8; q++) {
                float4 v = *(const float4*)(rowp + (q >> 1) * 32 + (q & 1) * 4);
                hjr[q * 4 + 0] = v.x; hjr[q * 4 + 1] = v.y;
                hjr[q * 4 + 2] = v.z; hjr[q * 4 + 3] = v.w;
            }
            #pragma unroll
            for (int kc = 0; kc < 4; kc++) {
                const float* pp = pre_sh + kc * 32 + quad * 8;
                v8s af;
                #pragma unroll
                for (int t = 0; t < 8; t++) {
                    float p = pp[t] + hjr[kc * 8 + t];
                    p = (p > 0.f) ? p : 0.f;
                    af[t] = (short)f2bs(p);
                }
                #pragma unroll
                for (int nt = 0; nt < 4; nt++) {
                    v8s bf = *(const v8s*)&bfr_g[(((nt * 4 + kc) * 64) + lane) * 8];
                    acc[nt] = __builtin_amdgcn_mfma_f32_16x16x32_bf16(
                        af, bf, acc[nt], 0, 0, 0);
                }
            }
            #pragma unroll
            for (int r = 0; r < 4; r++) {
                float s = 0.f;
                #pragma unroll
                for (int nt = 0; nt < 4; nt++) {
                    float v = acc[nt][r] + e2bv[nt];
                    if (v > 0.f) s += v * e3wv[nt];
                }
                red[(wv * 64 + ms * 16 + quad * 4 + r) * 17 + col] = s;
            }
        }
        __syncthreads();
        float s = e3b[0];
        for (int c = 0; c < 16; c++) s += red[tid * 17 + c];
        lg[bi * 256 + tid] = s;
    } else {
        float* f2row = smem;                         // 512 floats
        int r0 = (blk - 1024) * 4;
        for (int p = 0; p < 2; p++) {
            int idx = tid + p * 256;
            int r = r0 + (idx >> 7), n = idx & 127;
            const float* f1r = f1 + (long)r * 128;
            float s0 = 0.f, s1 = 0.f, s2 = 0.f, s3 = 0.f;
            #pragma unroll
            for (int k = 0; k < 128; k += 4) {
                float4 fv = *(const float4*)(f1r + k);
                s0 += fv.x * f2w[(k + 0) * 128 + n];
                s1 += fv.y * f2w[(k + 1) * 128 + n];
                s2 += fv.z * f2w[(k + 2) * 128 + n];
                s3 += fv.w * f2w[(k + 3) * 128 + n];
            }
            float s = f2b_[n] + ((s0 + s1) + (s2 + s3));
            if (s < 0.f) s = 0.f;
            f2row[idx] = s;
        }
        __syncthreads();
        if (tid < 24) {
            int r = tid / 6, c = tid % 6;
            float s = f3b[c];
            const float* fr = f2row + r * 128;
            for (int k = 0; k < 128; k++) s += fr[k] * f3w[k * 6 + c];
            out[262144 + (r0 + r) * 6 + c] = s;
        }
    }
}

// ---- L9: tiled symmetrize + sigmoid (32x32 tile pairs, LDS transpose) ----
__global__ void k_symsig(const float* lg, float* out) {
    __shared__ float Ta[32 * 33];
    __shared__ float Tb[32 * 33];
    int tid = threadIdx.x;
    int b = blockIdx.x / 36;
    int t = blockIdx.x % 36;
    int ti = 0, rem = t;
    while (rem >= 8 - ti) { rem -= 8 - ti; ti++; }
    int tj = ti + rem;
    int i0 = ti * 32, j0 = tj * 32;
    const float* lgb = lg + b * 65536;
    for (int p = 0; p < 4; p++) {
        int idx = p * 256 + tid;
        int r = idx >> 5, c = idx & 31;
        Ta[r * 33 + c] = lgb[(i0 + r) * 256 + j0 + c];
        Tb[r * 33 + c] = lgb[(j0 + r) * 256 + i0 + c];
    }
    __syncthreads();
    float* ob = out + b * 65536;
    for (int p = 0; p < 4; p++) {
        int idx = p * 256 + tid;
        int r = idx >> 5, c = idx & 31;
        float v1 = 0.5f * (Ta[r * 33 + c] + Tb[c * 33 + r]);
        ob[(i0 + r) * 256 + j0 + c] = 1.f / (1.f + expf(-v1));
        float v2 = 0.5f * (Tb[r * 33 + c] + Ta[c * 33 + r]);
        ob[(j0 + r) * 256 + i0 + c] = 1.f / (1.f + expf(-v2));
    }
}

extern "C" void kernel_launch(void* const* d_in, const int* in_sizes, int n_in,
                              void* d_out, int out_size, void* d_ws, size_t ws_size,
                              hipStream_t stream) {
    const float* x   = (const float*)d_in[0];
    const float* adj = (const float*)d_in[1];
    const float* W1  = (const float*)d_in[2];
    const float* b1  = (const float*)d_in[3];
    const float* W2  = (const float*)d_in[4];
    const float* b2  = (const float*)d_in[5];
    const float* W3  = (const float*)d_in[6];
    const float* b3  = (const float*)d_in[7];
    const float* g1  = (const float*)d_in[8];
    const float* be1 = (const float*)d_in[9];
    const float* g2  = (const float*)d_in[10];
    const float* be2 = (const float*)d_in[11];
    const float* e1w = (const float*)d_in[12];
    const float* e1b = (const float*)d_in[13];
    const float* e2w = (const float*)d_in[14];
    const float* e2b = (const float*)d_in[15];
    const float* e3w = (const float*)d_in[16];
    const float* e3b = (const float*)d_in[17];
    const float* f1w = (const float*)d_in[18];
    const float* f1b = (const float*)d_in[19];
    const float* f2w = (const float*)d_in[20];
    const float* f2b_ = (const float*)d_in[21];
    const float* f3w = (const float*)d_in[22];
    const float* f3b = (const float*)d_in[23];

    float* out = (float*)d_out;

    if (ws_size < (size_t)1600000 * 4) {
        hipMemsetAsync(d_out, 0x60, 4096, stream);   // diagnostic
        return;
    }
    float* ws = (float*)d_ws;
    float* st1 = ws;                        // 256 (zeroed in k_pre)
    float* st2 = ws + 256;                  // 256 (zeroed in k_pre)
    float* dg  = ws + 512;                  // 1024
    unsigned short* bfr_g = (unsigned short*)(ws + 1536);   // 8192 us
    float* An  = ws + 5632;                 // 262144 (materialized by L2)
    float* buf = An + 262144;
    float* hb  = buf + 262144;
    float* lg  = hb + 262144;
    float* h1  = lg + 262144;               // 131072 (later reused as f1)
    float* h2  = h1 + 131072;
    float* hi  = h2 + 131072;
    float* hj  = hi + 131072;               // contiguous after hi (batch-2)

    // L0: x@W1 + degree + e2w swizzle + zero BN accumulators
    k_pre<<<769, 256, 0, stream>>>(x, W1, adj, e2w, buf, dg, bfr_g, st1);
    // L2: h1 = norm(adj)@buf + b1 (+stats->st1); An materialized as byproduct
    k_tgemm<256><<<256, 256, 0, stream>>>(adj, buf, b1, dg, An, 0, 0, 0, st1, h1,
                                          128, 0, 65536, 32768, 32768, 4, 16);
    // L3: buf = BN(h1)@W2
    k_tgemm<128><<<256, 256, 0, stream>>>(h1, W2, 0, 0, 0, st1, g1, be1, 0, buf,
                                          128, 0, 0, 0, 0, 4, 64);
    // L4: h2 = An@buf + b2 (+stats -> st2)
    k_tgemm<256><<<256, 256, 0, stream>>>(An, buf, b2, 0, 0, 0, 0, 0, st2, h2,
                                          128, 0, 65536, 32768, 32768, 4, 16);
    // L5: buf = BN(h2)@W3
    k_tgemm<128><<<512, 256, 0, stream>>>(h2, W3, 0, 0, 0, st2, g2, be2, 0, buf,
                                          256, 0, 0, 0, 0, 8, 64);
    // L6: hb = relu(An@buf + b3)
    k_tgemm<256><<<512, 256, 0, stream>>>(An, buf, b3, 0, 0, 0, 0, 0, 0, hb,
                                          256, 1, 65536, 65536, 65536, 8, 16);
    // L7: hi/hj (batch-2) + f1 -> h1
    k_g67<<<768, 256, 0, stream>>>(hb, e1w, hi, f1w, f1b, h1);
    // L8: decoder + feature f2/f3
    k_decf<<<1280, 256, 0, stream>>>(hi, hj, e1b, bfr_g, e2b, e3w, e3b,
                                     h1, f2w, f2b_, f3w, f3b, lg, out);
    // L9: tiled symmetrize + sigmoid
    k_symsig<<<144, 256, 0, stream>>>(lg, out);
}